// Round 2
// 85.205 us; speedup vs baseline: 1.1954x; 1.1954x over previous
//
#include <hip/hip_runtime.h>
#include <math.h>

#define NPTS   8192
#define DDIM   128
#define NBLK   64            // 8192 / 128 row-blocks
#define NTRI   2080          // NBLK*(NBLK+1)/2 working blocks

using short8 = __attribute__((ext_vector_type(8))) short;
using f32x4  = __attribute__((ext_vector_type(4))) float;

__device__ __forceinline__ unsigned short f2bf(float f) {
    unsigned int u = __float_as_uint(f);
    u += 0x7fffu + ((u >> 16) & 1u);
    return (unsigned short)(u >> 16);
}
__device__ __forceinline__ float bf2f(unsigned short s) {
    return __uint_as_float(((unsigned int)s) << 16);
}

// async 16B/lane global->LDS DMA (dest = wave-uniform base + lane*16)
__device__ __forceinline__ void gld_lds16(const unsigned short* g, unsigned short* l) {
    __builtin_amdgcn_global_load_lds(
        (const __attribute__((address_space(1))) unsigned int*)g,
        (__attribute__((address_space(3))) unsigned int*)l,
        16, 0, 0);
}

// --- kernel 1: convert X -> bf16 once; sq[i] = ||bf16(x_i)||^2 ---
__global__ __launch_bounds__(256) void prep_kernel(
    const float* __restrict__ X, unsigned short* __restrict__ Xbf,
    float* __restrict__ sq)
{
    const int wave = threadIdx.x >> 6, lane = threadIdx.x & 63;
    const int row  = blockIdx.x * 4 + wave;
    float2 v = *(const float2*)(X + (size_t)row * DDIM + lane * 2);
    unsigned short a = f2bf(v.x), b = f2bf(v.y);
    float fa = bf2f(a), fb = bf2f(b);
    float s = fa * fa + fb * fb;
    *(ushort2*)(Xbf + (size_t)row * DDIM + lane * 2) = make_ushort2(a, b);
#pragma unroll
    for (int off = 32; off > 0; off >>= 1) s += __shfl_down(s, off);
    if (lane == 0) sq[row] = s;
}

// --- kernel 2: Gram tiles. A/B tiles DMA'd to LDS (swizzled), fragments via
// ds_read_b128. One barrier covers DMA + sq/lab publish.
// Grid: NTRI linear blocks, decoded to upper-triangle (bi, bj).
// LDS tile layout: half h (0=A,1=B), row r (0..127), 16B-slot s (0..15):
//   tile[h][r][s] holds X[rowbase_h + r][ 8*(s ^ (r&7)) .. +8 )   (XOR swizzle)
__global__ __launch_bounds__(256) void pair_kernel(
    const unsigned short* __restrict__ Xbf, const int* __restrict__ lab,
    const float* __restrict__ sq, float* __restrict__ slots /* [2][NTRI] */)
{
    const int k = blockIdx.x;
    int bi = (int)((129.0f - sqrtf((float)(16641 - 8 * k))) * 0.5f);
    if (bi < 0) bi = 0;
    while (64 * (bi + 1) - ((bi + 1) * bi) / 2 <= k) ++bi;   // O(bi+1) <= k
    while (64 * bi - (bi * (bi - 1)) / 2 > k) --bi;          // O(bi)   >  k
    const int bj = bi + (k - (64 * bi - (bi * (bi - 1)) / 2));

    __shared__ unsigned short tile[4096 * 8];   // 64 KB: A = bytes [0,32K), B = [32K,64K)
    __shared__ float sSqA[128], sSqB[128];
    __shared__ int   sLabA[128], sLabB[128];
    __shared__ float rP[4], rN[4];

    const int tid   = threadIdx.x;
    const int rowA0 = bi * 128;
    const int rowB0 = bj * 128;

    // ---- async staging, issued first so latency hides under sq/lab + barrier ----
    {
        const int rloc = tid >> 4;                        // 0..15: row within 16-row stripe
        const int cswz = ((tid & 15) ^ (rloc & 7)) * 8;   // pre-swizzled source column
        const unsigned short* gA = Xbf + (size_t)(rowA0 + rloc) * DDIM + cswz;
        const unsigned short* gB = Xbf + (size_t)(rowB0 + rloc) * DDIM + cswz;
        unsigned short* lbase = &tile[(size_t)(tid & ~63) * 8];  // wave-uniform
#pragma unroll
        for (int i = 0; i < 8; ++i)                       // A: rows i*16 + rloc
            gld_lds16(gA + (size_t)i * 16 * DDIM, lbase + i * 2048);
#pragma unroll
        for (int i = 0; i < 8; ++i)                       // B: rows i*16 + rloc
            gld_lds16(gB + (size_t)i * 16 * DDIM, lbase + 16384 + i * 2048);
    }

    if (tid < 128) {
        sSqA[tid]  = sq[rowA0 + tid];
        sLabA[tid] = lab[rowA0 + tid];
    } else {
        int t = tid - 128;
        sSqB[t]  = sq[rowB0 + t];
        sLabB[t] = lab[rowB0 + t];
    }
    __syncthreads();   // drains vmcnt (DMA) + lgkmcnt; the only staging barrier

    const int wave = tid >> 6, lane = tid & 63;
    const int quad = lane >> 4, rr = lane & 15;
    const int wr = wave >> 1, wc = wave & 1;
    const int r7 = rr & 7;

    // fragment bases: A row = wr*64 + t*16 + rr (t<4); row stride = 128 ushorts
    const unsigned short* tA = &tile[(size_t)(wr * 64 + rr) * 128];
    const unsigned short* tB = &tile[16384 + (size_t)(wc * 64 + rr) * 128];

    f32x4 acc[4][4];
#pragma unroll
    for (int i = 0; i < 4; ++i)
#pragma unroll
        for (int j = 0; j < 4; ++j)
            acc[i][j] = (f32x4){0.f, 0.f, 0.f, 0.f};

#pragma unroll
    for (int kc = 0; kc < 4; ++kc) {    // K = 128 in 4 chunks of 32
        const int s = (((kc * 4 + quad) ^ r7)) * 8;   // swizzled 16B slot
        short8 a[4], b[4];
#pragma unroll
        for (int t = 0; t < 4; ++t)
            a[t] = *(const short8*)(tA + t * 16 * 128 + s);
#pragma unroll
        for (int t = 0; t < 4; ++t)
            b[t] = *(const short8*)(tB + t * 16 * 128 + s);
#pragma unroll
        for (int i = 0; i < 4; ++i)
#pragma unroll
            for (int j = 0; j < 4; ++j)
                acc[i][j] = __builtin_amdgcn_mfma_f32_16x16x32_bf16(a[i], b[j], acc[i][j], 0, 0, 0);
    }

    // epilogue. C/D layout: col = lane&15, row = quad*4 + reg (verified)
    float sb[4]; int lbv[4];
#pragma unroll
    for (int j = 0; j < 4; ++j) {
        int cl = wc * 64 + j * 16 + rr;
        sb[j] = sSqB[cl];
        lbv[j] = sLabB[cl];
    }

    // fast path: pos-sum + min over diff-label distances (hinge active iff d+eps<4)
    float posS = 0.f, dmin = 1e30f;
#pragma unroll
    for (int i = 0; i < 4; ++i) {
#pragma unroll
        for (int rg = 0; rg < 4; ++rg) {
            int   rl = wr * 64 + i * 16 + quad * 4 + rg;
            float sa = sSqA[rl];
            int   la = sLabA[rl];
#pragma unroll
            for (int j = 0; j < 4; ++j) {
                float d = fmaxf(sa + sb[j] - 2.0f * acc[i][j][rg], 0.0f);
                bool same = (la == lbv[j]);
                posS += same ? d : 0.f;
                dmin = fminf(dmin, same ? 1e30f : d);
            }
        }
    }

    float negS = 0.f;
    if (__any(dmin + 1e-9f < 4.0f)) {   // rare: some hinge term is nonzero
#pragma unroll
        for (int i = 0; i < 4; ++i) {
#pragma unroll
            for (int rg = 0; rg < 4; ++rg) {
                int   rl = wr * 64 + i * 16 + quad * 4 + rg;
                float sa = sSqA[rl];
                int   la = sLabA[rl];
#pragma unroll
                for (int j = 0; j < 4; ++j) {
                    float d = fmaxf(sa + sb[j] - 2.0f * acc[i][j][rg], 0.0f);
                    float t = fmaxf(2.0f - sqrtf(d + 1e-9f), 0.f);
                    negS += (la == lbv[j]) ? 0.f : t * t;
                }
            }
        }
    }

    const float factor = (bi == bj) ? 1.0f : 2.0f;
    posS *= factor; negS *= factor;

#pragma unroll
    for (int off = 32; off > 0; off >>= 1) {
        posS += __shfl_down(posS, off);
        negS += __shfl_down(negS, off);
    }
    if (lane == 0) { rP[wave] = posS; rN[wave] = negS; }
    __syncthreads();
    if (tid == 0) {
        slots[k]        = rP[0] + rP[1] + rP[2] + rP[3];
        slots[NTRI + k] = rN[0] + rN[1] + rN[2] + rN[3];
    }
}

// --- kernel 3: label histogram (exact num_pos) + slot reduce + combine ---
__global__ __launch_bounds__(1024) void finalize_kernel(
    const float* __restrict__ slots, const int* __restrict__ lab,
    float* __restrict__ out)
{
    __shared__ int   hist[64];
    __shared__ float sP[16], sN[16];
    const int tid = threadIdx.x;
    if (tid < 64) hist[tid] = 0;
    __syncthreads();
    for (int i = tid; i < NPTS; i += 1024) atomicAdd(&hist[lab[i]], 1);

    float p = 0.f, n = 0.f;
    for (int i = tid; i < NTRI; i += 1024) { p += slots[i]; n += slots[NTRI + i]; }
#pragma unroll
    for (int off = 32; off > 0; off >>= 1) {
        p += __shfl_down(p, off);
        n += __shfl_down(n, off);
    }
    const int wave = tid >> 6, lane = tid & 63;
    if (lane == 0) { sP[wave] = p; sN[wave] = n; }
    __syncthreads();
    if (tid == 0) {
        long long np = 0;
        for (int c = 0; c < 64; ++c) np += (long long)hist[c] * hist[c];
        float tp = 0.f, tn = 0.f;
#pragma unroll
        for (int w = 0; w < 16; ++w) { tp += sP[w]; tn += sN[w]; }
        double dnp = (double)np;
        double dnn = (double)NPTS * (double)NPTS - dnp;
        double pt = (dnp > 0.0) ? 0.5 * (double)tp / dnp : 0.0;
        double nt = (dnn > 0.0) ? 0.5 * (double)tn / dnn : 0.0;
        out[0] = (float)(pt + nt);
    }
}

extern "C" void kernel_launch(void* const* d_in, const int* in_sizes, int n_in,
                              void* d_out, int out_size, void* d_ws, size_t ws_size,
                              hipStream_t stream) {
    const float* X   = (const float*)d_in[0];
    const int*   lab = (const int*)d_in[1];
    float*       out = (float*)d_out;

    char* ws = (char*)d_ws;
    unsigned short* Xbf   = (unsigned short*)(ws);                      // 2 MB
    float*          sq    = (float*)(ws + 2 * 1024 * 1024);             // 32 KB
    float*          slots = (float*)(ws + 2 * 1024 * 1024 + 32 * 1024); // 16.6 KB

    prep_kernel<<<NPTS / 4, 256, 0, stream>>>(X, Xbf, sq);
    pair_kernel<<<NTRI, 256, 0, stream>>>(Xbf, lab, sq, slots);
    finalize_kernel<<<1, 1024, 0, stream>>>(slots, lab, out);
}